// Round 1
// baseline (956.992 us; speedup 1.0000x reference)
//
#include <hip/hip_runtime.h>

#define T_SEQ 8192
#define NH 16
#define HD 64
#define DIM 1024
#define ROWS 16384   // 2*8192
#define CHK 256
#define NCHK 32

typedef float f32x4 __attribute__((ext_vector_type(4)));
typedef __bf16 bf16x8 __attribute__((ext_vector_type(8)));
typedef short short8 __attribute__((ext_vector_type(8)));
typedef short short4v __attribute__((ext_vector_type(4)));
typedef unsigned short ushort_t;

__device__ __forceinline__ float bf2f(ushort_t u){ return __uint_as_float(((unsigned)u)<<16); }
__device__ __forceinline__ ushort_t f2bf(float f){
  unsigned u = __float_as_uint(f);
  u += 0x7FFFu + ((u>>16)&1u);
  return (ushort_t)(u>>16);
}
#define BFLO(u) __uint_as_float((u)<<16)
#define BFHI(u) __uint_as_float((u)&0xFFFF0000u)

// ---------------- cast x (fp32 -> bf16) ----------------
__global__ __launch_bounds__(256) void cast_x_ker(const float* __restrict__ x,
                                                  ushort_t* __restrict__ xb){
  size_t i = ((size_t)blockIdx.x*256 + threadIdx.x)*8;
  float4 a = *(const float4*)&x[i];
  float4 b = *(const float4*)&x[i+4];
  ushort_t r[8] = { f2bf(a.x),f2bf(a.y),f2bf(a.z),f2bf(a.w),
                    f2bf(b.x),f2bf(b.y),f2bf(b.z),f2bf(b.w) };
  *(short8*)&xb[i] = *(short8*)r;
}

// ---------------- transpose weight 1024x1024 fp32 -> bf16 (N-major) ----------------
__global__ __launch_bounds__(256) void transpose_w(const float* __restrict__ W,
                                                   ushort_t* __restrict__ Wt){
  __shared__ float tile[64][65];
  int k0 = blockIdx.x*64, n0 = blockIdx.y*64;
  int tid = threadIdx.x;
  #pragma unroll
  for (int it=0; it<16; ++it){
    int idx = tid + it*256;
    int r = idx>>6, c = idx&63;
    tile[r][c] = W[(size_t)(k0+r)*DIM + n0+c];
  }
  __syncthreads();
  #pragma unroll
  for (int it=0; it<16; ++it){
    int idx = tid + it*256;
    int r = idx>>6, c = idx&63;
    Wt[(size_t)(n0+r)*DIM + k0+c] = f2bf(tile[c][r]);
  }
}

// ---------------- MFMA GEMM: C[M,N] = A[M,K] * Bt[N,K]^T ----------------
// 128x128 tile, BK=64, 4 waves (2x2), 16x16x32 bf16 MFMA, XOR-swizzled LDS.
template<int OUT_BF16>
__global__ __launch_bounds__(256,2) void gemm_bt(const ushort_t* __restrict__ A,
    const ushort_t* __restrict__ Bt, void* __restrict__ Cv, int M, int N, int K){
  __shared__ __align__(16) ushort_t As[128*64];
  __shared__ __align__(16) ushort_t Bs[128*64];
  int tid = threadIdx.x;
  int lane = tid & 63, wid = tid >> 6;
  int wr = wid >> 1, wc = wid & 1;
  int m0 = blockIdx.x * 128, n0 = blockIdx.y * 128;
  f32x4 acc[4][4] = {};
  int srow = tid >> 3;      // 0..31
  int sg = tid & 7;         // LDS granule slot
  const int nkt = K >> 6;
  for (int kt = 0; kt < nkt; ++kt){
    short8 ra[4], rb[4];
    #pragma unroll
    for (int s = 0; s < 4; ++s){
      int row = s*32 + srow;
      int gl = sg ^ (row & 7);   // pre-swizzled global source granule
      ra[s] = *(const short8*)&A[(size_t)(m0 + row)*K + kt*64 + gl*8];
      rb[s] = *(const short8*)&Bt[(size_t)(n0 + row)*K + kt*64 + gl*8];
    }
    __syncthreads();
    #pragma unroll
    for (int s = 0; s < 4; ++s){
      int row = s*32 + srow;
      *(short8*)&As[row*64 + sg*8] = ra[s];
      *(short8*)&Bs[row*64 + sg*8] = rb[s];
    }
    __syncthreads();
    #pragma unroll
    for (int kk = 0; kk < 2; ++kk){
      bf16x8 af[4], bfv[4];
      #pragma unroll
      for (int m = 0; m < 4; ++m){
        int row = wr*64 + m*16 + (lane & 15);
        int g = kk*4 + (lane >> 4);
        af[m] = *(const bf16x8*)&As[row*64 + ((g ^ (row & 7))<<3)];
      }
      #pragma unroll
      for (int n = 0; n < 4; ++n){
        int row = wc*64 + n*16 + (lane & 15);
        int g = kk*4 + (lane >> 4);
        bfv[n] = *(const bf16x8*)&Bs[row*64 + ((g ^ (row & 7))<<3)];
      }
      #pragma unroll
      for (int m = 0; m < 4; ++m)
        #pragma unroll
        for (int n = 0; n < 4; ++n)
          acc[m][n] = __builtin_amdgcn_mfma_f32_16x16x32_bf16(af[m], bfv[n], acc[m][n], 0,0,0);
    }
  }
  // epilogue: C/D layout col=lane&15, row=(lane>>4)*4+reg
  #pragma unroll
  for (int m = 0; m < 4; ++m){
    int row = m0 + wr*64 + m*16 + (lane>>4)*4;
    #pragma unroll
    for (int n = 0; n < 4; ++n){
      int col = n0 + wc*64 + n*16 + (lane & 15);
      #pragma unroll
      for (int r = 0; r < 4; ++r){
        float v = acc[m][n][r];
        if (OUT_BF16) ((ushort_t*)Cv)[(size_t)(row+r)*N + col] = f2bf(v);
        else          ((float*)Cv)[(size_t)(row+r)*N + col] = v;
      }
    }
  }
}

// ---------------- rmsnorm of q,k,v rows (in place, bf16) ----------------
__global__ __launch_bounds__(256) void rmsnorm_qkv(ushort_t* __restrict__ qkvg){
  int row = blockIdx.x; int tid = threadIdx.x;
  size_t base = (size_t)row*4096;
  __shared__ float red[4];
  int lane = tid&63, w = tid>>6;
  for (int mat=0; mat<3; ++mat){
    ushort_t* pp = &qkvg[base + mat*1024 + tid*4];
    short4v sv = *(const short4v*)pp;
    float v0 = bf2f((ushort_t)sv[0]), v1 = bf2f((ushort_t)sv[1]);
    float v2 = bf2f((ushort_t)sv[2]), v3 = bf2f((ushort_t)sv[3]);
    float ss = v0*v0+v1*v1+v2*v2+v3*v3;
    #pragma unroll
    for (int off=32; off>=1; off>>=1) ss += __shfl_xor(ss, off);
    if (lane==0) red[w] = ss;
    __syncthreads();
    float tot = red[0]+red[1]+red[2]+red[3];
    float rms = rsqrtf(tot*(1.f/1024.f)+1e-6f);
    short4v ov;
    ov[0]=(short)f2bf(v0*rms); ov[1]=(short)f2bf(v1*rms);
    ov[2]=(short)f2bf(v2*rms); ov[3]=(short)f2bf(v3*rms);
    *(short4v*)pp = ov;
    __syncthreads();
  }
}

// ---------------- gt = logsigmoid(x @ Wgt)/16, layout [b][h][t] ----------------
__global__ __launch_bounds__(256) void gt_ker(const float* __restrict__ x,
    const float* __restrict__ Wgt, float* __restrict__ gtb){
  int row = blockIdx.x; int b = row>>13; int t = row & (T_SEQ-1);
  int tid = threadIdx.x; int lane = tid&63; int w = tid>>6;
  __shared__ float xs[1024];
  #pragma unroll
  for (int i=0;i<4;++i) xs[tid+256*i] = x[(size_t)row*DIM + tid+256*i];
  __syncthreads();
  float a0=0,a1=0,a2=0,a3=0;
  #pragma unroll
  for (int jj=0;jj<16;++jj){
    int j = lane + 64*jj;
    float xv = xs[j];
    const float* wp = &Wgt[(size_t)j*NH + w*4];
    a0 += xv*wp[0]; a1 += xv*wp[1]; a2 += xv*wp[2]; a3 += xv*wp[3];
  }
  #pragma unroll
  for (int off=32; off>=1; off>>=1){
    a0 += __shfl_xor(a0, off); a1 += __shfl_xor(a1, off);
    a2 += __shfl_xor(a2, off); a3 += __shfl_xor(a3, off);
  }
  if (lane==0){
    float za[4] = {a0,a1,a2,a3};
    #pragma unroll
    for (int i=0;i<4;++i){
      float z = za[i];
      float ls = fminf(z,0.f) - log1pf(__expf(-fabsf(z)));
      gtb[((size_t)(b*NH + w*4 + i))*T_SEQ + t] = ls * (1.f/16.f);
    }
  }
}

// ---------------- attention phase 1: cumsum, B, kv = kd^T v ----------------
__global__ __launch_bounds__(256) void attn_p1(const ushort_t* __restrict__ qkvg,
    const float* __restrict__ gtb, float* __restrict__ bcb, float* __restrict__ Bb,
    float* __restrict__ kvb){
  int bid = blockIdx.x; int n = bid&31; int bh = bid>>5; int b = bh>>4; int h = bh&15;
  int t0 = n*CHK; int tid = threadIdx.x; int lane = tid&63; int w = tid>>6;
  __shared__ __align__(16) ushort_t vS[CHK*HD];
  __shared__ float wdec[CHK];
  __shared__ float wsum[4];
  float gv = gtb[(size_t)bh*T_SEQ + t0 + tid];
  float v = gv;
  #pragma unroll
  for (int off=1; off<64; off<<=1){ float u = __shfl_up(v, off); if (lane>=off) v += u; }
  if (lane==63) wsum[w] = v;
  __syncthreads();
  float pre=0;
  #pragma unroll
  for (int i=0;i<4;++i) if (i<w) pre += wsum[i];
  float bc = v + pre;
  float Bn = wsum[0]+wsum[1]+wsum[2]+wsum[3];
  bcb[(size_t)bh*T_SEQ + t0 + tid] = bc;
  wdec[tid] = __expf(Bn - bc);
  if (tid==0) Bb[bid] = Bn;
  size_t rowb = ((size_t)(b*T_SEQ + t0 + tid))*4096;
  #pragma unroll
  for (int e=0;e<HD;e+=8)
    *(short8*)&vS[tid*HD+e] = *(const short8*)&qkvg[rowb + 2048 + h*HD + e];
  __syncthreads();
  int d = lane; int e0h = w*8;  // 16 e-elements = 8 uints
  const unsigned* vS32 = (const unsigned*)vS;
  const ushort_t* kcol = &qkvg[((size_t)(b*T_SEQ+t0))*4096 + 1024 + h*HD + d];
  float acc[16] = {};
  #pragma unroll 4
  for (int j=0;j<CHK;++j){
    float kf = bf2f(kcol[(size_t)j*4096]) * wdec[j];
    #pragma unroll
    for (int dd=0; dd<8; ++dd){
      unsigned u = vS32[j*32 + e0h + dd];
      acc[2*dd]   += kf*BFLO(u);
      acc[2*dd+1] += kf*BFHI(u);
    }
  }
  float* kvp = &kvb[((size_t)bid*HD + d)*HD + w*16];
  #pragma unroll
  for (int e=0;e<16;++e) kvp[e] = acc[e];
}

// ---------------- sequential state scan over chunks ----------------
__global__ __launch_bounds__(256) void scan_ker(const float* __restrict__ kvb,
    const float* __restrict__ Bb, ushort_t* __restrict__ Sb){
  int bh = blockIdx.x; int tid = threadIdx.x;
  float S[16];
  #pragma unroll
  for (int i=0;i<16;++i) S[i]=0.f;
  int off = tid*16;
  for (int n=0;n<NCHK;++n){
    int cid = bh*NCHK + n;
    ushort_t* sp = &Sb[(size_t)cid*4096 + off];
    #pragma unroll
    for (int i=0;i<16;++i) sp[i] = f2bf(S[i]);   // state BEFORE this chunk
    float eB = __expf(Bb[cid]);
    const float* kp = &kvb[(size_t)cid*4096 + off];
    #pragma unroll
    for (int i=0;i<16;++i) S[i] = eB*S[i] + kp[i];
  }
}

// ---------------- attention phase 3: o = intra + cross, rmsnorm, silu(g)* ----------------
__global__ __launch_bounds__(256,2) void attn_p3(const ushort_t* __restrict__ qkvg,
    const float* __restrict__ bcb, const ushort_t* __restrict__ Sb,
    ushort_t* __restrict__ oact){
  int bid = blockIdx.x; int n = bid&31; int bh=bid>>5; int b=bh>>4; int h=bh&15;
  int t0=n*CHK; int tid=threadIdx.x;
  __shared__ __align__(16) ushort_t kS[CHK*HD];
  __shared__ __align__(16) ushort_t vS[CHK*HD];
  size_t rowb = ((size_t)(b*T_SEQ + t0 + tid))*4096;
  #pragma unroll
  for (int e=0;e<HD;e+=8){
    *(short8*)&kS[tid*HD+e] = *(const short8*)&qkvg[rowb + 1024 + h*HD + e];
    *(short8*)&vS[tid*HD+e] = *(const short8*)&qkvg[rowb + 2048 + h*HD + e];
  }
  float bc_i = bcb[(size_t)bh*T_SEQ + t0 + tid];
  __syncthreads();
  float o[64];
  #pragma unroll
  for (int e=0;e<64;++e) o[e]=0.f;
  float ebci = __expf(bc_i);
  // ---- cross: o += (q*scale*exp(bc_i)) @ S_prev (q streamed, db rolled) ----
  const uint4* Sp4 = (const uint4*)&Sb[(size_t)bid*4096];
  const uint4* qp4 = (const uint4*)&qkvg[rowb + h*HD];
  for (int db=0; db<8; ++db){
    uint4 qw = qp4[db];
    float qv[8];
    qv[0]=BFLO(qw.x); qv[1]=BFHI(qw.x); qv[2]=BFLO(qw.y); qv[3]=BFHI(qw.y);
    qv[4]=BFLO(qw.z); qv[5]=BFHI(qw.z); qv[6]=BFLO(qw.w); qv[7]=BFHI(qw.w);
    #pragma unroll
    for (int dd=0; dd<8; ++dd){
      float wq = qv[dd]*0.125f*ebci;
      #pragma unroll
      for (int k=0;k<8;++k){
        uint4 u = Sp4[(db*8+dd)*8 + k];
        o[k*8+0]+=wq*BFLO(u.x); o[k*8+1]+=wq*BFHI(u.x);
        o[k*8+2]+=wq*BFLO(u.y); o[k*8+3]+=wq*BFHI(u.y);
        o[k*8+4]+=wq*BFLO(u.z); o[k*8+5]+=wq*BFHI(u.z);
        o[k*8+6]+=wq*BFLO(u.w); o[k*8+7]+=wq*BFHI(u.w);
      }
    }
  }
  // ---- intra: q row in regs, k/v from LDS (broadcast reads) ----
  float q_r[64];
  #pragma unroll
  for (int k=0;k<8;++k){
    uint4 qw = qp4[k];
    q_r[k*8+0]=BFLO(qw.x)*0.125f; q_r[k*8+1]=BFHI(qw.x)*0.125f;
    q_r[k*8+2]=BFLO(qw.y)*0.125f; q_r[k*8+3]=BFHI(qw.y)*0.125f;
    q_r[k*8+4]=BFLO(qw.z)*0.125f; q_r[k*8+5]=BFHI(qw.z)*0.125f;
    q_r[k*8+6]=BFLO(qw.w)*0.125f; q_r[k*8+7]=BFHI(qw.w)*0.125f;
  }
  const float* bcp = &bcb[(size_t)bh*T_SEQ + t0];
  const unsigned* kS32 = (const unsigned*)kS;
  const unsigned* vS32 = (const unsigned*)vS;
  int i = tid;
  int jmax = ((tid>>6)+1)<<6;
  for (int j=0; j<jmax; ++j){
    float dot = 0.f;
    #pragma unroll
    for (int dd=0; dd<32; ++dd){
      unsigned u = kS32[j*32+dd];
      dot += q_r[2*dd]*BFLO(u) + q_r[2*dd+1]*BFHI(u);
    }
    float s = (j<=i) ? dot*__expf(bc_i - bcp[j]) : 0.f;
    #pragma unroll
    for (int dd=0; dd<32; ++dd){
      unsigned u = vS32[j*32+dd];
      o[2*dd]   += s*BFLO(u);
      o[2*dd+1] += s*BFHI(u);
    }
  }
  // ---- epilogue: rmsnorm over d=64, silu(g), write bf16 ----
  float ss=0.f;
  #pragma unroll
  for (int e=0;e<64;++e) ss += o[e]*o[e];
  float rms = rsqrtf(ss*(1.f/64.f)+1e-6f);
  const ushort_t* gp = &qkvg[rowb + 3072 + h*HD];
  ushort_t* op = &oact[(size_t)(b*T_SEQ+t0+tid)*DIM + h*HD];
  #pragma unroll
  for (int e=0;e<64;++e){
    float gf = bf2f(gp[e]);
    float sg = gf/(1.f+__expf(-gf));
    op[e] = f2bf(o[e]*rms*sg);
  }
}

// ---------------- launch ----------------
extern "C" void kernel_launch(void* const* d_in, const int* in_sizes, int n_in,
                              void* d_out, int out_size, void* d_ws, size_t ws_size,
                              hipStream_t stream){
  const float* x  = (const float*)d_in[0];
  const float* Wq = (const float*)d_in[1];
  const float* Wk = (const float*)d_in[2];
  const float* Wv = (const float*)d_in[3];
  const float* Wg = (const float*)d_in[4];
  const float* Wgt= (const float*)d_in[5];
  const float* Wo = (const float*)d_in[6];
  float* out = (float*)d_out;

  char* p = (char*)d_ws;
  ushort_t* xbf  = (ushort_t*)p; p += (size_t)ROWS*DIM*2;      // also reused as oact
  ushort_t* wcat = (ushort_t*)p; p += (size_t)4*DIM*DIM*2;
  ushort_t* wot  = (ushort_t*)p; p += (size_t)DIM*DIM*2;
  ushort_t* qkvg = (ushort_t*)p; p += (size_t)ROWS*4096*2;
  float* gtb = (float*)p; p += (size_t)32*T_SEQ*4;
  float* bcb = (float*)p; p += (size_t)32*T_SEQ*4;
  float* Bb  = (float*)p; p += 1024*4;
  float* kvb = (float*)p; p += (size_t)1024*4096*4;
  ushort_t* Sb = (ushort_t*)p; p += (size_t)1024*4096*2;
  ushort_t* oact = (ushort_t*)p; p += (size_t)ROWS*DIM*2;
  if ((size_t)(p - (char*)d_ws) > ws_size) return;

  cast_x_ker<<<(ROWS*DIM)/(256*8), 256, 0, stream>>>(x, xbf);
  transpose_w<<<dim3(16,16),256,0,stream>>>(Wq, wcat);
  transpose_w<<<dim3(16,16),256,0,stream>>>(Wk, wcat + (size_t)DIM*DIM);
  transpose_w<<<dim3(16,16),256,0,stream>>>(Wv, wcat + (size_t)2*DIM*DIM);
  transpose_w<<<dim3(16,16),256,0,stream>>>(Wg, wcat + (size_t)3*DIM*DIM);
  transpose_w<<<dim3(16,16),256,0,stream>>>(Wo, wot);
  gemm_bt<1><<<dim3(ROWS/128, 4096/128), 256, 0, stream>>>(xbf, wcat, qkvg, ROWS, 4096, DIM);
  rmsnorm_qkv<<<ROWS,256,0,stream>>>(qkvg);
  gt_ker<<<ROWS,256,0,stream>>>(x, Wgt, gtb);
  attn_p1<<<1024,256,0,stream>>>(qkvg, gtb, bcb, Bb, kvb);
  scan_ker<<<32,256,0,stream>>>(kvb, Bb, Sb);
  attn_p3<<<1024,256,0,stream>>>(qkvg, bcb, Sb, oact);
  gemm_bt<0><<<dim3(ROWS/128, 1024/128), 256, 0, stream>>>(oact, wot, out, ROWS, 1024, DIM);
}

// Round 2
// 446.023 us; speedup vs baseline: 2.1456x; 2.1456x over previous
//
#include <hip/hip_runtime.h>

#define T_SEQ 8192
#define NH 16
#define HD 64
#define DIM 1024
#define ROWS 16384   // 2*8192
#define CHK 256
#define NCHK 32

typedef float f32x4 __attribute__((ext_vector_type(4)));
typedef __bf16 bf16x8 __attribute__((ext_vector_type(8)));
typedef short short8 __attribute__((ext_vector_type(8)));
typedef short short4v __attribute__((ext_vector_type(4)));
typedef unsigned short ushort_t;

__device__ __forceinline__ float bf2f(ushort_t u){ return __uint_as_float(((unsigned)u)<<16); }
__device__ __forceinline__ ushort_t f2bf(float f){
  unsigned u = __float_as_uint(f);
  u += 0x7FFFu + ((u>>16)&1u);
  return (ushort_t)(u>>16);
}
#define BFLO(u) __uint_as_float((u)<<16)
#define BFHI(u) __uint_as_float((u)&0xFFFF0000u)
#define MFMA16(a,b,c) __builtin_amdgcn_mfma_f32_16x16x32_bf16((a),(b),(c),0,0,0)

// ---------------- cast x (fp32 -> bf16) ----------------
__global__ __launch_bounds__(256) void cast_x_ker(const float* __restrict__ x,
                                                  ushort_t* __restrict__ xb){
  size_t i = ((size_t)blockIdx.x*256 + threadIdx.x)*8;
  float4 a = *(const float4*)&x[i];
  float4 b = *(const float4*)&x[i+4];
  ushort_t r[8] = { f2bf(a.x),f2bf(a.y),f2bf(a.z),f2bf(a.w),
                    f2bf(b.x),f2bf(b.y),f2bf(b.z),f2bf(b.w) };
  *(short8*)&xb[i] = *(short8*)r;
}

// ---------------- transpose weight 1024x1024 fp32 -> bf16 (N-major) ----------------
__global__ __launch_bounds__(256) void transpose_w(const float* __restrict__ W,
                                                   ushort_t* __restrict__ Wt){
  __shared__ float tile[64][65];
  int k0 = blockIdx.x*64, n0 = blockIdx.y*64;
  int tid = threadIdx.x;
  #pragma unroll
  for (int it=0; it<16; ++it){
    int idx = tid + it*256;
    int r = idx>>6, c = idx&63;
    tile[r][c] = W[(size_t)(k0+r)*DIM + n0+c];
  }
  __syncthreads();
  #pragma unroll
  for (int it=0; it<16; ++it){
    int idx = tid + it*256;
    int r = idx>>6, c = idx&63;
    Wt[(size_t)(n0+r)*DIM + k0+c] = f2bf(tile[c][r]);
  }
}

// ---------------- MFMA GEMM: C[M,N] = A[M,K] * Bt[N,K]^T ----------------
template<int OUT_BF16>
__global__ __launch_bounds__(256,2) void gemm_bt(const ushort_t* __restrict__ A,
    const ushort_t* __restrict__ Bt, void* __restrict__ Cv, int M, int N, int K){
  __shared__ __align__(16) ushort_t As[128*64];
  __shared__ __align__(16) ushort_t Bs[128*64];
  int tid = threadIdx.x;
  int lane = tid & 63, wid = tid >> 6;
  int wr = wid >> 1, wc = wid & 1;
  int m0 = blockIdx.x * 128, n0 = blockIdx.y * 128;
  f32x4 acc[4][4] = {};
  int srow = tid >> 3;
  int sg = tid & 7;
  const int nkt = K >> 6;
  for (int kt = 0; kt < nkt; ++kt){
    short8 ra[4], rb[4];
    #pragma unroll
    for (int s = 0; s < 4; ++s){
      int row = s*32 + srow;
      int gl = sg ^ (row & 7);
      ra[s] = *(const short8*)&A[(size_t)(m0 + row)*K + kt*64 + gl*8];
      rb[s] = *(const short8*)&Bt[(size_t)(n0 + row)*K + kt*64 + gl*8];
    }
    __syncthreads();
    #pragma unroll
    for (int s = 0; s < 4; ++s){
      int row = s*32 + srow;
      *(short8*)&As[row*64 + sg*8] = ra[s];
      *(short8*)&Bs[row*64 + sg*8] = rb[s];
    }
    __syncthreads();
    #pragma unroll
    for (int kk = 0; kk < 2; ++kk){
      bf16x8 af[4], bfv[4];
      #pragma unroll
      for (int m = 0; m < 4; ++m){
        int row = wr*64 + m*16 + (lane & 15);
        int g = kk*4 + (lane >> 4);
        af[m] = *(const bf16x8*)&As[row*64 + ((g ^ (row & 7))<<3)];
      }
      #pragma unroll
      for (int n = 0; n < 4; ++n){
        int row = wc*64 + n*16 + (lane & 15);
        int g = kk*4 + (lane >> 4);
        bfv[n] = *(const bf16x8*)&Bs[row*64 + ((g ^ (row & 7))<<3)];
      }
      #pragma unroll
      for (int m = 0; m < 4; ++m)
        #pragma unroll
        for (int n = 0; n < 4; ++n)
          acc[m][n] = MFMA16(af[m], bfv[n], acc[m][n]);
    }
  }
  #pragma unroll
  for (int m = 0; m < 4; ++m){
    int row = m0 + wr*64 + m*16 + (lane>>4)*4;
    #pragma unroll
    for (int n = 0; n < 4; ++n){
      int col = n0 + wc*64 + n*16 + (lane & 15);
      #pragma unroll
      for (int r = 0; r < 4; ++r){
        float v = acc[m][n][r];
        if (OUT_BF16) ((ushort_t*)Cv)[(size_t)(row+r)*N + col] = f2bf(v);
        else          ((float*)Cv)[(size_t)(row+r)*N + col] = v;
      }
    }
  }
}

// ---------------- rmsnorm of q,k,v rows (in place, bf16) ----------------
__global__ __launch_bounds__(256) void rmsnorm_qkv(ushort_t* __restrict__ qkvg){
  int row = blockIdx.x; int tid = threadIdx.x;
  size_t base = (size_t)row*4096;
  __shared__ float red[4];
  int lane = tid&63, w = tid>>6;
  for (int mat=0; mat<3; ++mat){
    ushort_t* pp = &qkvg[base + mat*1024 + tid*4];
    short4v sv = *(const short4v*)pp;
    float v0 = bf2f((ushort_t)sv[0]), v1 = bf2f((ushort_t)sv[1]);
    float v2 = bf2f((ushort_t)sv[2]), v3 = bf2f((ushort_t)sv[3]);
    float ss = v0*v0+v1*v1+v2*v2+v3*v3;
    #pragma unroll
    for (int off=32; off>=1; off>>=1) ss += __shfl_xor(ss, off);
    if (lane==0) red[w] = ss;
    __syncthreads();
    float tot = red[0]+red[1]+red[2]+red[3];
    float rms = rsqrtf(tot*(1.f/1024.f)+1e-6f);
    short4v ov;
    ov[0]=(short)f2bf(v0*rms); ov[1]=(short)f2bf(v1*rms);
    ov[2]=(short)f2bf(v2*rms); ov[3]=(short)f2bf(v3*rms);
    *(short4v*)pp = ov;
    __syncthreads();
  }
}

// ---------------- gt = logsigmoid(x @ Wgt)/16, layout [b][h][t] ----------------
__global__ __launch_bounds__(256) void gt_ker(const float* __restrict__ x,
    const float* __restrict__ Wgt, float* __restrict__ gtb){
  int row = blockIdx.x; int b = row>>13; int t = row & (T_SEQ-1);
  int tid = threadIdx.x; int lane = tid&63; int w = tid>>6;
  __shared__ float xs[1024];
  #pragma unroll
  for (int i=0;i<4;++i) xs[tid+256*i] = x[(size_t)row*DIM + tid+256*i];
  __syncthreads();
  float a0=0,a1=0,a2=0,a3=0;
  #pragma unroll
  for (int jj=0;jj<16;++jj){
    int j = lane + 64*jj;
    float xv = xs[j];
    const float* wp = &Wgt[(size_t)j*NH + w*4];
    a0 += xv*wp[0]; a1 += xv*wp[1]; a2 += xv*wp[2]; a3 += xv*wp[3];
  }
  #pragma unroll
  for (int off=32; off>=1; off>>=1){
    a0 += __shfl_xor(a0, off); a1 += __shfl_xor(a1, off);
    a2 += __shfl_xor(a2, off); a3 += __shfl_xor(a3, off);
  }
  if (lane==0){
    float za[4] = {a0,a1,a2,a3};
    #pragma unroll
    for (int i=0;i<4;++i){
      float z = za[i];
      float ls = fminf(z,0.f) - log1pf(__expf(-fabsf(z)));
      gtb[((size_t)(b*NH + w*4 + i))*T_SEQ + t] = ls * (1.f/16.f);
    }
  }
}

// ---------------- attention phase 1 (MFMA): kv = kd^T v ----------------
__global__ __launch_bounds__(256,2) void attn_p1(const ushort_t* __restrict__ qkvg,
    const float* __restrict__ gtb, float* __restrict__ Bb, float* __restrict__ kvb){
  __shared__ __align__(16) ushort_t sh2[32768];   // 64 KB: kdT [64][256] | vT [64][256], both swizzled
  ushort_t* kdt = sh2;
  ushort_t* vt  = sh2 + 16384;
  float* tmp = (float*)sh2;   // overlay, used only around the cumsum
  int bid = blockIdx.x; int n = bid&31; int bh = bid>>5; int b = bh>>4; int h = bh&15;
  int t0 = n*CHK; int tid = threadIdx.x; int lane = tid&63; int w = tid>>6;
  // cumsum of gt over chunk
  float vscan = gtb[(size_t)bh*T_SEQ + t0 + tid];
  #pragma unroll
  for (int off=1; off<64; off<<=1){ float u = __shfl_up(vscan, off); if (lane>=off) vscan += u; }
  if (lane==63) tmp[w] = vscan;
  __syncthreads();
  float pre=0;
  #pragma unroll
  for (int i=0;i<4;++i) if (i<w) pre += tmp[i];
  float bc = vscan + pre;
  float Bn = tmp[0]+tmp[1]+tmp[2]+tmp[3];
  if (tid==0) Bb[bid] = Bn;
  __syncthreads();           // tmp reads done before kdt overwrite
  // build kdT = (k*exp(B-bc))^T and vT, swizzled
  {
    int j = tid;
    size_t rowb = ((size_t)(b*T_SEQ + t0 + j))*4096;
    float sj = __expf(Bn - bc);
    #pragma unroll
    for (int q8=0; q8<8; ++q8){
      short8 k8 = *(const short8*)&qkvg[rowb + 1024 + h*HD + q8*8];
      short8 v8 = *(const short8*)&qkvg[rowb + 2048 + h*HD + q8*8];
      #pragma unroll
      for (int kk=0; kk<8; ++kk){
        int d = q8*8 + kk;
        kdt[(d<<8) + (((j>>3)^(d&7))<<3) + (j&7)] = f2bf(bf2f((ushort_t)k8[kk])*sj);
        vt [(d<<8) + (((j>>3)^(d&7))<<3) + (j&7)] = (ushort_t)v8[kk];
      }
    }
  }
  __syncthreads();
  // kv[d][e] = sum_j kd[j][d] v[j][e]
  f32x4 acc[4] = {};
  #pragma unroll
  for (int s=0; s<8; ++s){
    int d = w*16 + (lane&15);
    int jj = s*32 + (lane>>4)*8;
    bf16x8 ka = *(const bf16x8*)&kdt[(d<<8) + (((jj>>3)^(d&7))<<3)];
    #pragma unroll
    for (int et=0; et<4; ++et){
      int e = et*16 + (lane&15);
      bf16x8 vf = *(const bf16x8*)&vt[(e<<8) + (((jj>>3)^(e&7))<<3)];
      acc[et] = MFMA16(ka, vf, acc[et]);
    }
  }
  float* kvp = &kvb[(size_t)bid*4096];
  #pragma unroll
  for (int et=0; et<4; ++et)
    #pragma unroll
    for (int r=0; r<4; ++r)
      kvp[(w*16 + (lane>>4)*4 + r)*64 + et*16 + (lane&15)] = acc[et][r];
}

// ---------------- sequential state scan; stores S^T (bf16) ----------------
__global__ __launch_bounds__(256) void scan_ker(const float* __restrict__ kvb,
    const float* __restrict__ Bb, ushort_t* __restrict__ Sb){
  int bh = blockIdx.x; int tid = threadIdx.x;
  float S[16];
  #pragma unroll
  for (int i=0;i<16;++i) S[i]=0.f;
  int d = tid>>2, e0 = (tid&3)*16;
  for (int n=0;n<NCHK;++n){
    int cid = bh*NCHK + n;
    #pragma unroll
    for (int i=0;i<16;++i)
      Sb[(size_t)cid*4096 + (e0+i)*64 + d] = f2bf(S[i]);   // transposed: [e][d]
    float eB = __expf(Bb[cid]);
    const float* kp = &kvb[(size_t)cid*4096 + d*64 + e0];
    #pragma unroll
    for (int i=0;i<16;++i) S[i] = eB*S[i] + kp[i];
  }
}

// ---------------- attention phase 3 (MFMA): intra + cross + rmsnorm + silu ----------------
__global__ __launch_bounds__(512,2) void attn_p3(const ushort_t* __restrict__ qkvg,
    const float* __restrict__ gtb, const ushort_t* __restrict__ Sb,
    ushort_t* __restrict__ oact){
  // LDS: vT 32768 B | P 16384 B (8 waves x [32][32]) | bcs 1024 B | tmp 32 B
  __shared__ __align__(16) ushort_t sh[(32768+16384+1024+32)/2];
  ushort_t* vt = sh;                     // [e=64][j=256] swizzled
  ushort_t* ps = sh + 16384;             // per-wave [32][32] swizzled
  float* bcs = (float*)(sh + 24576);
  float* tmp = (float*)(sh + 25088);
  int bid = blockIdx.x; int n = bid&31; int bh = bid>>5; int b = bh>>4; int h = bh&15;
  int t0 = n*CHK; int tid = threadIdx.x; int lane = tid&63; int w = tid>>6;
  // ---- bc cumsum (threads 0..255) ----
  float vscan = 0.f;
  if (tid < 256){
    vscan = gtb[(size_t)bh*T_SEQ + t0 + tid];
    #pragma unroll
    for (int off=1; off<64; off<<=1){ float u = __shfl_up(vscan, off); if (lane>=off) vscan += u; }
    if (lane==63) tmp[w] = vscan;
  }
  __syncthreads();
  if (tid < 256){
    float pre=0;
    #pragma unroll
    for (int i=0;i<4;++i) if (i<w) pre += tmp[i];
    bcs[tid] = vscan + pre;
  }
  // ---- build vT (all 512 threads) ----
  {
    int j = tid>>1, ehalf = tid&1;
    size_t rowb = ((size_t)(b*T_SEQ + t0 + j))*4096;
    #pragma unroll
    for (int q8=0; q8<4; ++q8){
      short8 v8 = *(const short8*)&qkvg[rowb + 2048 + h*HD + ehalf*32 + q8*8];
      #pragma unroll
      for (int kk=0; kk<8; ++kk){
        int e = ehalf*32 + q8*8 + kk;
        vt[(e<<8) + (((j>>3)^(e&7))<<3) + (j&7)] = (ushort_t)v8[kk];
      }
    }
  }
  __syncthreads();
  // ---- per-wave: rows [w*32, w*32+32) of the chunk ----
  int wrow = w*32;
  size_t chunkbase = (size_t)b*T_SEQ + t0;
  // q fragments (resident)
  bf16x8 qf[2][2];
  #pragma unroll
  for (int rt=0; rt<2; ++rt)
    #pragma unroll
    for (int s=0; s<2; ++s)
      qf[rt][s] = *(const bf16x8*)&qkvg[(chunkbase + wrow + rt*16 + (lane&15))*4096
                                        + h*HD + s*32 + (lane>>4)*8];
  // cross: O = q @ S^T  (S^T from global, [e][d])
  f32x4 o_[2][4] = {};
  #pragma unroll
  for (int s=0; s<2; ++s)
    #pragma unroll
    for (int et=0; et<4; ++et){
      bf16x8 stf = *(const bf16x8*)&Sb[(size_t)bid*4096 + (et*16 + (lane&15))*64
                                       + s*32 + (lane>>4)*8];
      #pragma unroll
      for (int rt=0; rt<2; ++rt)
        o_[rt][et] = MFMA16(qf[rt][s], stf, o_[rt][et]);
    }
  // scale cross rows by 0.125*exp(bc_i)
  #pragma unroll
  for (int rt=0; rt<2; ++rt)
    #pragma unroll
    for (int rr=0; rr<4; ++rr){
      float fs = 0.125f*__expf(bcs[wrow + rt*16 + (lane>>4)*4 + rr]);
      #pragma unroll
      for (int et=0; et<4; ++et) o_[rt][et][rr] *= fs;
    }
  // ---- intra: half-blocks of 32 cols ----
  for (int hb=0; hb<=w; ++hb){
    int jb = hb>>1, ch = hb&1;
    int jbase = jb*64 + ch*32;
    float mb = bcs[jb*64];
    float r8[2][4];
    #pragma unroll
    for (int rt=0; rt<2; ++rt)
      #pragma unroll
      for (int rr=0; rr<4; ++rr)
        r8[rt][rr] = 0.125f*__expf(bcs[wrow + rt*16 + (lane>>4)*4 + rr] - mb);
    float c2[2];
    #pragma unroll
    for (int ct=0; ct<2; ++ct)
      c2[ct] = __expf(mb - bcs[jbase + ct*16 + (lane&15)]);
    // scores
    f32x4 s2[2][2] = {};
    #pragma unroll
    for (int s=0; s<2; ++s)
      #pragma unroll
      for (int ct=0; ct<2; ++ct){
        bf16x8 kf = *(const bf16x8*)&qkvg[(chunkbase + jbase + ct*16 + (lane&15))*4096
                                          + 1024 + h*HD + s*32 + (lane>>4)*8];
        #pragma unroll
        for (int rt=0; rt<2; ++rt)
          s2[rt][ct] = MFMA16(qf[rt][s], kf, s2[rt][ct]);
      }
    // mask + decay + store P (bf16, swizzled)
    bool dia = (hb == w);
    #pragma unroll
    for (int rt=0; rt<2; ++rt)
      #pragma unroll
      for (int ct=0; ct<2; ++ct)
        #pragma unroll
        for (int rr=0; rr<4; ++rr){
          int pi = rt*16 + (lane>>4)*4 + rr;
          int pj = ct*16 + (lane&15);
          float pv = s2[rt][ct][rr] * r8[rt][rr] * c2[ct];
          if (dia && (jbase + pj) > (wrow + pi)) pv = 0.f;
          ps[w*1024 + pi*32 + (((pj>>3) ^ ((pi>>2)&3))<<3) + (pj&7)] = f2bf(pv);
        }
    // PV
    bf16x8 vf[4];
    #pragma unroll
    for (int et=0; et<4; ++et){
      int e = et*16 + (lane&15);
      int jj = jbase + (lane>>4)*8;
      vf[et] = *(const bf16x8*)&vt[(e<<8) + (((jj>>3) ^ (e&7))<<3)];
    }
    bf16x8 pf[2];
    #pragma unroll
    for (int rt=0; rt<2; ++rt){
      int i = rt*16 + (lane&15);
      pf[rt] = *(const bf16x8*)&ps[w*1024 + i*32 + (((lane>>4) ^ ((i>>2)&3))<<3)];
    }
    #pragma unroll
    for (int rt=0; rt<2; ++rt)
      #pragma unroll
      for (int et=0; et<4; ++et)
        o_[rt][et] = MFMA16(pf[rt], vf[et], o_[rt][et]);
  }
  // ---- epilogue: per-row rmsnorm (d=64), silu(g), coalesced store ----
  float rms8[2][4];
  #pragma unroll
  for (int rt=0; rt<2; ++rt)
    #pragma unroll
    for (int rr=0; rr<4; ++rr){
      float ssq = 0.f;
      #pragma unroll
      for (int et=0; et<4; ++et){ float xx = o_[rt][et][rr]; ssq += xx*xx; }
      ssq += __shfl_xor(ssq,1); ssq += __shfl_xor(ssq,2);
      ssq += __shfl_xor(ssq,4); ssq += __shfl_xor(ssq,8);
      rms8[rt][rr] = rsqrtf(ssq*(1.f/64.f)+1e-6f);
    }
  #pragma unroll
  for (int eh=0; eh<2; ++eh){
    #pragma unroll
    for (int rt=0; rt<2; ++rt)
      #pragma unroll
      for (int e2=0; e2<2; ++e2){
        int et = eh*2 + e2;
        #pragma unroll
        for (int rr=0; rr<4; ++rr){
          int pi = rt*16 + (lane>>4)*4 + rr;
          int pj = e2*16 + (lane&15);
          ps[w*1024 + pi*32 + (((pj>>3) ^ ((pi>>2)&3))<<3) + (pj&7)] =
            f2bf(o_[rt][et][rr]*rms8[rt][rr]);
        }
      }
    int i2 = lane&31, e16 = (lane>>5)*16;
    int gr0 = e16>>3;
    int f = (i2>>2)&3;
    short8 ov0 = *(const short8*)&ps[w*1024 + i2*32 + ((gr0^f)<<3)];
    short8 ov1 = *(const short8*)&ps[w*1024 + i2*32 + (((gr0+1)^f)<<3)];
    size_t rowg = chunkbase + wrow + i2;
    short8 gv0 = *(const short8*)&qkvg[rowg*4096 + 3072 + h*HD + eh*32 + e16];
    short8 gv1 = *(const short8*)&qkvg[rowg*4096 + 3072 + h*HD + eh*32 + e16 + 8];
    ushort_t outv[16];
    #pragma unroll
    for (int k=0;k<8;++k){
      float gf = bf2f((ushort_t)gv0[k]);
      float sg = gf/(1.f+__expf(-gf));
      outv[k] = f2bf(bf2f((ushort_t)ov0[k])*sg);
    }
    #pragma unroll
    for (int k=0;k<8;++k){
      float gf = bf2f((ushort_t)gv1[k]);
      float sg = gf/(1.f+__expf(-gf));
      outv[8+k] = f2bf(bf2f((ushort_t)ov1[k])*sg);
    }
    ushort_t* op = &oact[rowg*DIM + h*HD + eh*32 + e16];
    *(short8*)&op[0] = *(short8*)&outv[0];
    *(short8*)&op[8] = *(short8*)&outv[8];
  }
}

// ---------------- launch ----------------
extern "C" void kernel_launch(void* const* d_in, const int* in_sizes, int n_in,
                              void* d_out, int out_size, void* d_ws, size_t ws_size,
                              hipStream_t stream){
  const float* x  = (const float*)d_in[0];
  const float* Wq = (const float*)d_in[1];
  const float* Wk = (const float*)d_in[2];
  const float* Wv = (const float*)d_in[3];
  const float* Wg = (const float*)d_in[4];
  const float* Wgt= (const float*)d_in[5];
  const float* Wo = (const float*)d_in[6];
  float* out = (float*)d_out;

  char* p = (char*)d_ws;
  ushort_t* xbf  = (ushort_t*)p; p += (size_t)ROWS*DIM*2;
  ushort_t* wcat = (ushort_t*)p; p += (size_t)4*DIM*DIM*2;
  ushort_t* wot  = (ushort_t*)p; p += (size_t)DIM*DIM*2;
  ushort_t* qkvg = (ushort_t*)p; p += (size_t)ROWS*4096*2;
  float* gtb = (float*)p; p += (size_t)32*T_SEQ*4;
  float* Bb  = (float*)p; p += 1024*4;
  float* kvb = (float*)p; p += (size_t)1024*4096*4;
  ushort_t* Sb = (ushort_t*)p; p += (size_t)1024*4096*2;
  ushort_t* oact = (ushort_t*)p; p += (size_t)ROWS*DIM*2;
  if ((size_t)(p - (char*)d_ws) > ws_size) return;

  cast_x_ker<<<(ROWS*DIM)/(256*8), 256, 0, stream>>>(x, xbf);
  transpose_w<<<dim3(16,16),256,0,stream>>>(Wq, wcat);
  transpose_w<<<dim3(16,16),256,0,stream>>>(Wk, wcat + (size_t)DIM*DIM);
  transpose_w<<<dim3(16,16),256,0,stream>>>(Wv, wcat + (size_t)2*DIM*DIM);
  transpose_w<<<dim3(16,16),256,0,stream>>>(Wg, wcat + (size_t)3*DIM*DIM);
  transpose_w<<<dim3(16,16),256,0,stream>>>(Wo, wot);
  gemm_bt<1><<<dim3(ROWS/128, 4096/128), 256, 0, stream>>>(xbf, wcat, qkvg, ROWS, 4096, DIM);
  rmsnorm_qkv<<<ROWS,256,0,stream>>>(qkvg);
  gt_ker<<<ROWS,256,0,stream>>>(x, Wgt, gtb);
  attn_p1<<<1024,256,0,stream>>>(qkvg, gtb, Bb, kvb);
  scan_ker<<<32,256,0,stream>>>(kvb, Bb, Sb);
  attn_p3<<<1024,512,0,stream>>>(qkvg, gtb, Sb, oact);
  gemm_bt<0><<<dim3(ROWS/128, 1024/128), 256, 0, stream>>>(oact, wot, out, ROWS, 1024, DIM);
}